// Round 17
// baseline (283.280 us; speedup 1.0000x reference)
//
#include <hip/hip_runtime.h>

#define HID 64

__device__ __forceinline__ float bf2f(unsigned short u) {
    return __uint_as_float(((unsigned)u) << 16);
}
__device__ __forceinline__ unsigned short f2bf(float f) {
    unsigned u = __float_as_uint(f);
    u += 0x7FFF + ((u >> 16) & 1);  // RNE
    return (unsigned short)(u >> 16);
}

// ================= CSR build =================
// XCD-partitioned (R10-verified: random cross-XCD 4B atomics cost a 64B line
// writeback each; blockIdx&7 keeps each slice in ONE XCD's L2).
// R14 lesson: NO cooperative kernel here — grid.sync cost 4x the dispatch
// gaps AND broke the %8 block->XCD mapping (WRITE 6->57MB).
__global__ void hist_part(const int* __restrict__ dst, int* __restrict__ counts,
                          int E, int nodes_per, int chunk) {
    int p = blockIdx.x & 7;          // partition = presumed XCD
    int q = blockIdx.x >> 3;
    int lo = p * nodes_per;
    int hi = lo + nodes_per;
    int beg = q * chunk;
    int end = min(beg + chunk, E);
    for (int e = beg + threadIdx.x; e < end; e += 256) {
        int d = dst[e];
        if (d >= lo && d < hi) atomicAdd(&counts[d], 1);
    }
}

// Fused scan: per-block LDS scan, block totals published via
// atomicExch(total+1), predecessors polled (196 blocks co-resident).
__global__ void scan_fused(const int* __restrict__ counts, int* __restrict__ bsum,
                           int* __restrict__ rowptr, int* __restrict__ cursor,
                           float* __restrict__ dinv, int n) {
    __shared__ int s[256];
    __shared__ int pre[256];
    int t = threadIdx.x;
    int b = blockIdx.x;
    int i = b * 256 + t;
    int v = (i < n) ? counts[i] : 0;
    if (i < n) dinv[i] = rsqrtf((float)v + 1.0f);  // deg incl. self-loop
    s[t] = v;
    __syncthreads();
#pragma unroll
    for (int d = 1; d < 256; d <<= 1) {
        int x = (t >= d) ? s[t - d] : 0;
        __syncthreads();
        s[t] += x;
        __syncthreads();
    }
    if (t == 255) atomicExch(&bsum[b], s[255] + 1);   // publish
    int myp = 0;
    if (t < b) {
        int val;
        do { val = atomicAdd(&bsum[t], 0); } while (val == 0);
        myp = val - 1;
    }
    pre[t] = myp;
    __syncthreads();
#pragma unroll
    for (int d = 128; d > 0; d >>= 1) {
        if (t < d) pre[t] += pre[t + d];
        __syncthreads();
    }
    int boffb = pre[0];
    if (i < n) {
        int r = s[t] - v + boffb;   // exclusive prefix
        rowptr[i] = r;
        cursor[i] = r;
    }
    if (i == n - 1) rowptr[n] = s[t] + boffb;  // == E
}

// ================= fused fill + input GEMM (independent work, 1 dispatch) ===
__global__ void fill_gemm(const int* __restrict__ eidx, int* __restrict__ cursor,
                          int* __restrict__ col, int E, int n, int nodes_per,
                          int chunk, int fillBlocks,
                          const float* __restrict__ x, const float* __restrict__ Win,
                          const float* __restrict__ bin, const float* __restrict__ W,
                          const float* __restrict__ dinv, float* __restrict__ h,
                          unsigned short* __restrict__ hws) {
    if (blockIdx.x < fillBlocks) {
        int p = blockIdx.x & 7;
        int q = blockIdx.x >> 3;
        const int* __restrict__ dst = eidx + E;
        int lo = p * nodes_per;
        int hi = lo + nodes_per;
        int beg = q * chunk;
        int end = min(beg + chunk, E);
        for (int e = beg + threadIdx.x; e < end; e += 256) {
            int d = dst[e];
            if (d >= lo && d < hi) {
                int s = eidx[e];
                int pos = atomicAdd(&cursor[d], 1);
                col[pos] = s;
            }
        }
        return;
    }
    __shared__ float wl[64 * 64];
    __shared__ float winl[256];
    __shared__ float binl[64];
    __shared__ float hl[256];
    int b = blockIdx.x - fillBlocks;
    int tid = threadIdx.x;
#pragma unroll
    for (int i = 0; i < 16; ++i) wl[tid + 256 * i] = W[tid + 256 * i];
    winl[tid] = Win[tid];
    if (tid < 64) binl[tid] = bin[tid];
    int j = tid & 63;
    int w = tid >> 6;
    for (int c = 0; c < 8; ++c) {
        int v = b * 32 + c * 4 + w;
        __syncthreads();
        float hv = 0.f;
        if (v < n) {
            float4 xv = *(const float4*)&x[(size_t)v * 4];  // wave-uniform
            hv = binl[j] + xv.x * winl[j] + xv.y * winl[64 + j]
                         + xv.z * winl[128 + j] + xv.w * winl[192 + j];
            __builtin_nontemporal_store(hv, &h[(size_t)v * 64 + j]);
        }
        hl[tid] = hv;
        __syncthreads();
        if (v < n) {
            const float* hr = &hl[w * 64];  // wave-uniform -> LDS broadcast
            float acc = 0.f;
#pragma unroll
            for (int k = 0; k < 64; ++k) acc += hr[k] * wl[k * 64 + j];
            __builtin_nontemporal_store(f2bf(acc * dinv[v]), &hws[(size_t)v * 64 + j]);
        }
    }
}

// R12 gather body (PROVEN best: 4 concurrent edge streams/wave, 8-way unroll.
// R13's wave-cooperative variant regressed — concurrency > balance here).
#define GATHER_BODY(hws4, col, beg, end, s0, s1, s2, s3, gl)                      \
    {                                                                             \
        int e = beg;                                                              \
        for (; e + 7 < end; e += 8) {                                             \
            int c0 = col[e], c1 = col[e+1], c2 = col[e+2], c3 = col[e+3];         \
            int c4 = col[e+4], c5 = col[e+5], c6 = col[e+6], c7 = col[e+7];       \
            ushort4 m0 = hws4[(size_t)c0 * 16 + gl];                              \
            ushort4 m1 = hws4[(size_t)c1 * 16 + gl];                              \
            ushort4 m2 = hws4[(size_t)c2 * 16 + gl];                              \
            ushort4 m3 = hws4[(size_t)c3 * 16 + gl];                              \
            ushort4 m4 = hws4[(size_t)c4 * 16 + gl];                              \
            ushort4 m5 = hws4[(size_t)c5 * 16 + gl];                              \
            ushort4 m6 = hws4[(size_t)c6 * 16 + gl];                              \
            ushort4 m7 = hws4[(size_t)c7 * 16 + gl];                              \
            s0 += bf2f(m0.x)+bf2f(m1.x)+bf2f(m2.x)+bf2f(m3.x)                     \
                + bf2f(m4.x)+bf2f(m5.x)+bf2f(m6.x)+bf2f(m7.x);                    \
            s1 += bf2f(m0.y)+bf2f(m1.y)+bf2f(m2.y)+bf2f(m3.y)                     \
                + bf2f(m4.y)+bf2f(m5.y)+bf2f(m6.y)+bf2f(m7.y);                    \
            s2 += bf2f(m0.z)+bf2f(m1.z)+bf2f(m2.z)+bf2f(m3.z)                     \
                + bf2f(m4.z)+bf2f(m5.z)+bf2f(m6.z)+bf2f(m7.z);                    \
            s3 += bf2f(m0.w)+bf2f(m1.w)+bf2f(m2.w)+bf2f(m3.w)                     \
                + bf2f(m4.w)+bf2f(m5.w)+bf2f(m6.w)+bf2f(m7.w);                    \
        }                                                                         \
        for (; e + 3 < end; e += 4) {                                             \
            int c0 = col[e], c1 = col[e+1], c2 = col[e+2], c3 = col[e+3];         \
            ushort4 m0 = hws4[(size_t)c0 * 16 + gl];                              \
            ushort4 m1 = hws4[(size_t)c1 * 16 + gl];                              \
            ushort4 m2 = hws4[(size_t)c2 * 16 + gl];                              \
            ushort4 m3 = hws4[(size_t)c3 * 16 + gl];                              \
            s0 += bf2f(m0.x)+bf2f(m1.x)+bf2f(m2.x)+bf2f(m3.x);                    \
            s1 += bf2f(m0.y)+bf2f(m1.y)+bf2f(m2.y)+bf2f(m3.y);                    \
            s2 += bf2f(m0.z)+bf2f(m1.z)+bf2f(m2.z)+bf2f(m3.z);                    \
            s3 += bf2f(m0.w)+bf2f(m1.w)+bf2f(m2.w)+bf2f(m3.w);                    \
        }                                                                         \
        for (; e < end; ++e) {                                                    \
            ushort4 me = hws4[(size_t)col[e] * 16 + gl];                          \
            s0 += bf2f(me.x); s1 += bf2f(me.y); s2 += bf2f(me.z); s3 += bf2f(me.w);\
        }                                                                         \
    }

// gather + BN + ReLU + residual, then NEXT layer's GEMM from LDS.
// W staged as bf16 (8KB not 16KB): LDS 12.25KB -> 8 blocks/CU (was 7).
// Occupancy is the one untested gather lever (unroll/balance/banks all
// neutral); bf16 W rounds weights RNE — absmax budget 0.03 << 0.099.
__global__ void gather_gemm(const int* __restrict__ rowptr, const int* __restrict__ col,
                            const unsigned short* __restrict__ hws_in,
                            const float* __restrict__ dinv, float* __restrict__ h,
                            const float* __restrict__ cb, const float* __restrict__ gamma,
                            const float* __restrict__ beta, const float* __restrict__ mean,
                            const float* __restrict__ var, const float* __restrict__ Wn,
                            unsigned short* __restrict__ hws_out, int n) {
    __shared__ unsigned short wl16[64 * 64];
    __shared__ float hl[16 * 64];
    int tid = threadIdx.x;
#pragma unroll
    for (int i = 0; i < 16; ++i) {
        int idx = tid + 256 * i;
        wl16[idx] = f2bf(Wn[idx]);
    }
    int lane = tid & 63, wave = tid >> 6;
    int grp = lane >> 4, gl = lane & 15;
    int ln = wave * 4 + grp;                 // local node 0..15
    int v = blockIdx.x * 16 + ln;
    bool valid = v < n;
    int vv = valid ? v : 0;
    int j0 = gl * 4;
    const ushort4* hws4 = (const ushort4*)hws_in;
    ushort4 m = hws4[(size_t)vv * 16 + gl];  // self term (already * dinv[v])
    float s0 = bf2f(m.x), s1 = bf2f(m.y), s2 = bf2f(m.z), s3 = bf2f(m.w);
    int beg = rowptr[vv];
    int end = valid ? rowptr[vv + 1] : beg;
    GATHER_BODY(hws4, col, beg, end, s0, s1, s2, s3, gl)
    float di = dinv[vv];
    float4 cbv = *(const float4*)&cb[j0];
    float4 mnv = *(const float4*)&mean[j0];
    float4 vrv = *(const float4*)&var[j0];
    float4 gmv = *(const float4*)&gamma[j0];
    float4 btv = *(const float4*)&beta[j0];
    float4 hres = *(const float4*)&h[(size_t)vv * 64 + j0];
    float4 o;
    o.x = fmaxf((s0 * di + cbv.x - mnv.x) * rsqrtf(vrv.x + 1e-5f) * gmv.x + btv.x, 0.f) + hres.x;
    o.y = fmaxf((s1 * di + cbv.y - mnv.y) * rsqrtf(vrv.y + 1e-5f) * gmv.y + btv.y, 0.f) + hres.y;
    o.z = fmaxf((s2 * di + cbv.z - mnv.z) * rsqrtf(vrv.z + 1e-5f) * gmv.z + btv.z, 0.f) + hres.z;
    o.w = fmaxf((s3 * di + cbv.w - mnv.w) * rsqrtf(vrv.w + 1e-5f) * gmv.w + btv.w, 0.f) + hres.w;
    if (valid) *(float4*)&h[(size_t)vv * 64 + j0] = o;
    *(float4*)&hl[ln * 64 + j0] = o;          // deposit row for GEMM phase
    __syncthreads();
    // ---- next-layer GEMM from LDS: wave w -> nodes 4w..4w+3, 1 acc each
    // (PROVEN single-accumulator loop — R3/R5 spilled with multi-acc) ----
    int j = lane;
    for (int c = 0; c < 4; ++c) {
        int ln2 = wave * 4 + c;
        int v2 = blockIdx.x * 16 + ln2;
        if (v2 < n) {
            const float* hr = &hl[ln2 * 64];  // wave-uniform -> broadcast
            float acc = 0.f;
#pragma unroll
            for (int k = 0; k < 64; ++k) acc += hr[k] * bf2f(wl16[k * 64 + j]);
            hws_out[(size_t)v2 * 64 + j] = f2bf(acc * dinv[v2]);
        }
    }
}

// gather + BN + ReLU + residual (layer 2), then MLP head.
// W1 bf16 in LDS + shfl-butterfly W2 head (no tl): 13.25KB -> 8 blocks/CU.
__global__ void gather_mlp(const int* __restrict__ rowptr, const int* __restrict__ col,
                           const unsigned short* __restrict__ hws_in,
                           const float* __restrict__ dinv, const float* __restrict__ h,
                           const float* __restrict__ cb, const float* __restrict__ gamma,
                           const float* __restrict__ beta, const float* __restrict__ mean,
                           const float* __restrict__ var, const float* __restrict__ x,
                           const float* __restrict__ W1, const float* __restrict__ b1,
                           const float* __restrict__ W2, const float* __restrict__ b2,
                           float* __restrict__ out, int n) {
    __shared__ unsigned short wl16[64 * 64];
    __shared__ float w2l[256];
    __shared__ float hl[16 * 64];
    int tid = threadIdx.x;
#pragma unroll
    for (int i = 0; i < 16; ++i) {
        int idx = tid + 256 * i;
        wl16[idx] = f2bf(W1[idx]);
    }
    w2l[tid] = W2[tid];
    int lane = tid & 63, wave = tid >> 6;
    int grp = lane >> 4, gl = lane & 15;
    int ln = wave * 4 + grp;
    int v = blockIdx.x * 16 + ln;
    bool valid = v < n;
    int vv = valid ? v : 0;
    int j0 = gl * 4;
    const ushort4* hws4 = (const ushort4*)hws_in;
    ushort4 m = hws4[(size_t)vv * 16 + gl];
    float s0 = bf2f(m.x), s1 = bf2f(m.y), s2 = bf2f(m.z), s3 = bf2f(m.w);
    int beg = rowptr[vv];
    int end = valid ? rowptr[vv + 1] : beg;
    GATHER_BODY(hws4, col, beg, end, s0, s1, s2, s3, gl)
    float di = dinv[vv];
    float4 cbv = *(const float4*)&cb[j0];
    float4 mnv = *(const float4*)&mean[j0];
    float4 vrv = *(const float4*)&var[j0];
    float4 gmv = *(const float4*)&gamma[j0];
    float4 btv = *(const float4*)&beta[j0];
    float4 hres = *(const float4*)&h[(size_t)vv * 64 + j0];
    float4 o;
    o.x = fmaxf((s0 * di + cbv.x - mnv.x) * rsqrtf(vrv.x + 1e-5f) * gmv.x + btv.x, 0.f) + hres.x;
    o.y = fmaxf((s1 * di + cbv.y - mnv.y) * rsqrtf(vrv.y + 1e-5f) * gmv.y + btv.y, 0.f) + hres.y;
    o.z = fmaxf((s2 * di + cbv.z - mnv.z) * rsqrtf(vrv.z + 1e-5f) * gmv.z + btv.z, 0.f) + hres.z;
    o.w = fmaxf((s3 * di + cbv.w - mnv.w) * rsqrtf(vrv.w + 1e-5f) * gmv.w + btv.w, 0.f) + hres.w;
    *(float4*)&hl[ln * 64 + j0] = o;
    __syncthreads();
    // ---- MLP head: t = relu(h@W1+b1); out = x + t@W2 + b2.
    // Per node: single-acc dot from LDS, then shfl-butterfly for W2 (R6-proven).
    int j = lane;
    float b1j = b1[j];
    float w20 = w2l[j * 4 + 0], w21 = w2l[j * 4 + 1];
    float w22 = w2l[j * 4 + 2], w23 = w2l[j * 4 + 3];
    for (int c = 0; c < 4; ++c) {
        int ln2 = wave * 4 + c;
        int v2 = blockIdx.x * 16 + ln2;
        const float* hr = &hl[ln2 * 64];      // broadcast
        float acc = b1j;
#pragma unroll
        for (int k = 0; k < 64; ++k) acc += hr[k] * bf2f(wl16[k * 64 + j]);
        float tj = fmaxf(acc, 0.f);
        float p0 = tj * w20, p1 = tj * w21, p2 = tj * w22, p3 = tj * w23;
#pragma unroll
        for (int mm = 32; mm >= 1; mm >>= 1) {
            p0 += __shfl_xor(p0, mm, 64);
            p1 += __shfl_xor(p1, mm, 64);
            p2 += __shfl_xor(p2, mm, 64);
            p3 += __shfl_xor(p3, mm, 64);
        }
        if (v2 < n && j < 4) {
            float pp = (j == 0) ? p0 : (j == 1) ? p1 : (j == 2) ? p2 : p3;
            out[(size_t)v2 * 4 + j] = x[(size_t)v2 * 4 + j] + pp + b2[j];
        }
    }
}

extern "C" void kernel_launch(void* const* d_in, const int* in_sizes, int n_in,
                              void* d_out, int out_size, void* d_ws, size_t ws_size,
                              hipStream_t stream) {
    const float* x     = (const float*)d_in[0];
    const int*   eidx  = (const int*)  d_in[1];
    const float* Win   = (const float*)d_in[2];
    const float* bin   = (const float*)d_in[3];
    const float* convw = (const float*)d_in[4];
    const float* convb = (const float*)d_in[5];
    const float* gamma = (const float*)d_in[6];
    const float* beta  = (const float*)d_in[7];
    const float* mean  = (const float*)d_in[8];
    const float* var   = (const float*)d_in[9];
    const float* W1    = (const float*)d_in[10];
    const float* b1    = (const float*)d_in[11];
    const float* W2    = (const float*)d_in[12];
    const float* b2    = (const float*)d_in[13];
    float* out = (float*)d_out;

    int n = in_sizes[0] / 4;   // 50000
    int E = in_sizes[1] / 2;   // 800000
    const int B = 256;
    int NB = (n + B - 1) / B;  // 196

    // workspace layout (counts|bsum adjacent -> one memset):
    // dinv[n] | h[n*64] | hws0 bf16 | hws1 bf16 | counts[n] | bsum[256] |
    // cursor[n] | rowptr[n+1] | col[E]
    char* p = (char*)d_ws;
    size_t nh = (size_t)n * 64;
    float*          dinv   = (float*)p;          p += ((size_t)n + 16) * 4;
    float*          h      = (float*)p;          p += nh * 4;
    unsigned short* hws0   = (unsigned short*)p; p += nh * 2;
    unsigned short* hws1   = (unsigned short*)p; p += nh * 2;
    int*            counts = (int*)p;            p += (size_t)n * 4;
    int*            bsum   = (int*)p;            p += 256 * 4;
    int*            cursor = (int*)p;            p += (size_t)n * 4;
    int*            rowptr = (int*)p;            p += ((size_t)n + 16) * 4;
    int*            col    = (int*)p;            p += (size_t)E * 4;

    const int GP = 128;                       // blocks per partition
    int fillBlocks = GP * 8;                  // 1024
    int nodes_per = (n + 7) / 8;
    int chunk = (E + GP - 1) / GP;

    // ---- CSR build head (3 dispatches incl. memset) ----
    hipMemsetAsync(counts, 0, ((size_t)n + 256) * 4, stream);  // counts + bsum
    hist_part<<<fillBlocks, B, 0, stream>>>(eidx + E, counts, E, nodes_per, chunk);
    scan_fused<<<NB, B, 0, stream>>>(counts, bsum, rowptr, cursor, dinv, n);

    // ---- fill + input GEMM fused (independent work, 1 dispatch) ----
    int NB32 = (n + 31) / 32;
    fill_gemm<<<fillBlocks + NB32, B, 0, stream>>>(
        eidx, cursor, col, E, n, nodes_per, chunk, fillBlocks,
        x, Win, bin, convw, dinv, h, hws0);

    // ---- layers (3 dispatches) ----
    int NB16 = (n + 15) / 16;
    gather_gemm<<<NB16, B, 0, stream>>>(rowptr, col, hws0, dinv, h,
        convb, gamma, beta, mean, var, convw + 4096, hws1, n);
    gather_gemm<<<NB16, B, 0, stream>>>(rowptr, col, hws1, dinv, h,
        convb + 64, gamma + 64, beta + 64, mean + 64, var + 64, convw + 8192, hws0, n);
    gather_mlp<<<NB16, B, 0, stream>>>(rowptr, col, hws0, dinv, h,
        convb + 128, gamma + 128, beta + 128, mean + 128, var + 128,
        x, W1, b1, W2, b2, out, n);
}

// Round 18
// 272.475 us; speedup vs baseline: 1.0397x; 1.0397x over previous
//
#include <hip/hip_runtime.h>

#define HID 64

__device__ __forceinline__ float bf2f(unsigned short u) {
    return __uint_as_float(((unsigned)u) << 16);
}
__device__ __forceinline__ unsigned short f2bf(float f) {
    unsigned u = __float_as_uint(f);
    u += 0x7FFF + ((u >> 16) & 1);  // RNE
    return (unsigned short)(u >> 16);
}

// ================= CSR build =================
// XCD-partitioned (R10-verified: random cross-XCD 4B atomics cost a 64B line
// writeback each; blockIdx&7 keeps each slice in ONE XCD's L2).
// R14 lesson: NO cooperative kernel here — grid.sync cost 4x the dispatch
// gaps AND broke the %8 block->XCD mapping (WRITE 6->57MB).
__global__ void hist_part(const int* __restrict__ dst, int* __restrict__ counts,
                          int E, int nodes_per, int chunk) {
    int p = blockIdx.x & 7;          // partition = presumed XCD
    int q = blockIdx.x >> 3;
    int lo = p * nodes_per;
    int hi = lo + nodes_per;
    int beg = q * chunk;
    int end = min(beg + chunk, E);
    for (int e = beg + threadIdx.x; e < end; e += 256) {
        int d = dst[e];
        if (d >= lo && d < hi) atomicAdd(&counts[d], 1);
    }
}

__global__ void scan1(const int* __restrict__ counts, int* __restrict__ tmp,
                      int* __restrict__ bsum, float* __restrict__ dinv, int n) {
    __shared__ int s[256];
    int t = threadIdx.x;
    int i = blockIdx.x * 256 + t;
    int v = (i < n) ? counts[i] : 0;
    if (i < n) dinv[i] = rsqrtf((float)v + 1.0f);  // deg incl. self-loop
    s[t] = v;
    __syncthreads();
#pragma unroll
    for (int d = 1; d < 256; d <<= 1) {
        int x = (t >= d) ? s[t - d] : 0;
        __syncthreads();
        s[t] += x;
        __syncthreads();
    }
    if (i < n) tmp[i] = s[t];
    if (t == 255) bsum[blockIdx.x] = s[255];
}

// rowptr + cursor, scan2 folded in (block prefix via LDS tree reduce).
__global__ void scan3b(const int* __restrict__ counts, const int* __restrict__ tmp,
                       const int* __restrict__ bsum, int* __restrict__ rowptr,
                       int* __restrict__ cursor, int n, int nb) {
    __shared__ int sb[256];
    int t = threadIdx.x;
    int b = blockIdx.x;
    sb[t] = (t < b && t < nb) ? bsum[t] : 0;
    __syncthreads();
#pragma unroll
    for (int d = 128; d > 0; d >>= 1) {
        if (t < d) sb[t] += sb[t + d];
        __syncthreads();
    }
    int boffb = sb[0];
    int i = b * 256 + t;
    if (i < n) {
        int r = tmp[i] - counts[i] + boffb;
        rowptr[i] = r;
        cursor[i] = r;
    }
    if (i == n - 1) rowptr[n] = tmp[i] + boffb;  // == E
}

// ================= fused fill + input GEMM (independent work, 1 dispatch) ===
// Blocks 0..fillBlocks-1: XCD-partitioned bucket fill (same blockIdx&7
// semantics as the standalone version -> partition heuristic intact).
// Blocks >= fillBlocks: input_proj + layer0 GEMM (PROVEN single-accumulator
// inner loop — R3/R5 spilled with multi-acc; do not change).
__global__ void fill_gemm(const int* __restrict__ eidx, int* __restrict__ cursor,
                          int* __restrict__ col, int E, int n, int nodes_per,
                          int chunk, int fillBlocks,
                          const float* __restrict__ x, const float* __restrict__ Win,
                          const float* __restrict__ bin, const float* __restrict__ W,
                          const float* __restrict__ dinv, float* __restrict__ h,
                          unsigned short* __restrict__ hws) {
    if (blockIdx.x < fillBlocks) {
        int p = blockIdx.x & 7;
        int q = blockIdx.x >> 3;
        const int* __restrict__ dst = eidx + E;
        int lo = p * nodes_per;
        int hi = lo + nodes_per;
        int beg = q * chunk;
        int end = min(beg + chunk, E);
        for (int e = beg + threadIdx.x; e < end; e += 256) {
            int d = dst[e];
            if (d >= lo && d < hi) {
                int s = eidx[e];
                int pos = atomicAdd(&cursor[d], 1);
                col[pos] = s;
            }
        }
        return;
    }
    __shared__ float wl[64 * 64];
    __shared__ float winl[256];
    __shared__ float binl[64];
    __shared__ float hl[256];
    int b = blockIdx.x - fillBlocks;
    int tid = threadIdx.x;
#pragma unroll
    for (int i = 0; i < 16; ++i) wl[tid + 256 * i] = W[tid + 256 * i];
    winl[tid] = Win[tid];
    if (tid < 64) binl[tid] = bin[tid];
    int j = tid & 63;
    int w = tid >> 6;
    for (int c = 0; c < 8; ++c) {
        int v = b * 32 + c * 4 + w;
        __syncthreads();
        float hv = 0.f;
        if (v < n) {
            float4 xv = *(const float4*)&x[(size_t)v * 4];  // wave-uniform
            hv = binl[j] + xv.x * winl[j] + xv.y * winl[64 + j]
                         + xv.z * winl[128 + j] + xv.w * winl[192 + j];
            h[(size_t)v * 64 + j] = hv;
        }
        hl[tid] = hv;
        __syncthreads();
        if (v < n) {
            const float* hr = &hl[w * 64];  // wave-uniform -> LDS broadcast
            float acc = 0.f;
#pragma unroll
            for (int k = 0; k < 64; ++k) acc += hr[k] * wl[k * 64 + j];
            hws[(size_t)v * 64 + j] = f2bf(acc * dinv[v]);
        }
    }
}

// R12 gather body (PROVEN best: 4 concurrent edge streams/wave, 8-way unroll.
// R13's wave-cooperative variant regressed — concurrency > balance here.
// R17: occupancy lever also neutral — gather is bound by the memory system's
// random-line service rate; all software levers tested).
#define GATHER_BODY(hws4, col, beg, end, s0, s1, s2, s3, gl)                      \
    {                                                                             \
        int e = beg;                                                              \
        for (; e + 7 < end; e += 8) {                                             \
            int c0 = col[e], c1 = col[e+1], c2 = col[e+2], c3 = col[e+3];         \
            int c4 = col[e+4], c5 = col[e+5], c6 = col[e+6], c7 = col[e+7];       \
            ushort4 m0 = hws4[(size_t)c0 * 16 + gl];                              \
            ushort4 m1 = hws4[(size_t)c1 * 16 + gl];                              \
            ushort4 m2 = hws4[(size_t)c2 * 16 + gl];                              \
            ushort4 m3 = hws4[(size_t)c3 * 16 + gl];                              \
            ushort4 m4 = hws4[(size_t)c4 * 16 + gl];                              \
            ushort4 m5 = hws4[(size_t)c5 * 16 + gl];                              \
            ushort4 m6 = hws4[(size_t)c6 * 16 + gl];                              \
            ushort4 m7 = hws4[(size_t)c7 * 16 + gl];                              \
            s0 += bf2f(m0.x)+bf2f(m1.x)+bf2f(m2.x)+bf2f(m3.x)                     \
                + bf2f(m4.x)+bf2f(m5.x)+bf2f(m6.x)+bf2f(m7.x);                    \
            s1 += bf2f(m0.y)+bf2f(m1.y)+bf2f(m2.y)+bf2f(m3.y)                     \
                + bf2f(m4.y)+bf2f(m5.y)+bf2f(m6.y)+bf2f(m7.y);                    \
            s2 += bf2f(m0.z)+bf2f(m1.z)+bf2f(m2.z)+bf2f(m3.z)                     \
                + bf2f(m4.z)+bf2f(m5.z)+bf2f(m6.z)+bf2f(m7.z);                    \
            s3 += bf2f(m0.w)+bf2f(m1.w)+bf2f(m2.w)+bf2f(m3.w)                     \
                + bf2f(m4.w)+bf2f(m5.w)+bf2f(m6.w)+bf2f(m7.w);                    \
        }                                                                         \
        for (; e + 3 < end; e += 4) {                                             \
            int c0 = col[e], c1 = col[e+1], c2 = col[e+2], c3 = col[e+3];         \
            ushort4 m0 = hws4[(size_t)c0 * 16 + gl];                              \
            ushort4 m1 = hws4[(size_t)c1 * 16 + gl];                              \
            ushort4 m2 = hws4[(size_t)c2 * 16 + gl];                              \
            ushort4 m3 = hws4[(size_t)c3 * 16 + gl];                              \
            s0 += bf2f(m0.x)+bf2f(m1.x)+bf2f(m2.x)+bf2f(m3.x);                    \
            s1 += bf2f(m0.y)+bf2f(m1.y)+bf2f(m2.y)+bf2f(m3.y);                    \
            s2 += bf2f(m0.z)+bf2f(m1.z)+bf2f(m2.z)+bf2f(m3.z);                    \
            s3 += bf2f(m0.w)+bf2f(m1.w)+bf2f(m2.w)+bf2f(m3.w);                    \
        }                                                                         \
        for (; e < end; ++e) {                                                    \
            ushort4 me = hws4[(size_t)col[e] * 16 + gl];                          \
            s0 += bf2f(me.x); s1 += bf2f(me.y); s2 += bf2f(me.z); s3 += bf2f(me.w);\
        }                                                                         \
    }

// gather + BN + ReLU + residual, then NEXT layer's GEMM from LDS.
__global__ void gather_gemm(const int* __restrict__ rowptr, const int* __restrict__ col,
                            const unsigned short* __restrict__ hws_in,
                            const float* __restrict__ dinv, float* __restrict__ h,
                            const float* __restrict__ cb, const float* __restrict__ gamma,
                            const float* __restrict__ beta, const float* __restrict__ mean,
                            const float* __restrict__ var, const float* __restrict__ Wn,
                            unsigned short* __restrict__ hws_out, int n) {
    __shared__ float wl[64 * 64];
    __shared__ float hl[16 * 64];
    int tid = threadIdx.x;
#pragma unroll
    for (int i = 0; i < 16; ++i) wl[tid + 256 * i] = Wn[tid + 256 * i];
    int lane = tid & 63, wave = tid >> 6;
    int grp = lane >> 4, gl = lane & 15;
    int ln = wave * 4 + grp;                 // local node 0..15
    int v = blockIdx.x * 16 + ln;
    bool valid = v < n;
    int vv = valid ? v : 0;
    int j0 = gl * 4;
    const ushort4* hws4 = (const ushort4*)hws_in;
    ushort4 m = hws4[(size_t)vv * 16 + gl];  // self term (already * dinv[v])
    float s0 = bf2f(m.x), s1 = bf2f(m.y), s2 = bf2f(m.z), s3 = bf2f(m.w);
    int beg = rowptr[vv];
    int end = valid ? rowptr[vv + 1] : beg;
    GATHER_BODY(hws4, col, beg, end, s0, s1, s2, s3, gl)
    float di = dinv[vv];
    float4 cbv = *(const float4*)&cb[j0];
    float4 mnv = *(const float4*)&mean[j0];
    float4 vrv = *(const float4*)&var[j0];
    float4 gmv = *(const float4*)&gamma[j0];
    float4 btv = *(const float4*)&beta[j0];
    float4 hres = *(const float4*)&h[(size_t)vv * 64 + j0];
    float4 o;
    o.x = fmaxf((s0 * di + cbv.x - mnv.x) * rsqrtf(vrv.x + 1e-5f) * gmv.x + btv.x, 0.f) + hres.x;
    o.y = fmaxf((s1 * di + cbv.y - mnv.y) * rsqrtf(vrv.y + 1e-5f) * gmv.y + btv.y, 0.f) + hres.y;
    o.z = fmaxf((s2 * di + cbv.z - mnv.z) * rsqrtf(vrv.z + 1e-5f) * gmv.z + btv.z, 0.f) + hres.z;
    o.w = fmaxf((s3 * di + cbv.w - mnv.w) * rsqrtf(vrv.w + 1e-5f) * gmv.w + btv.w, 0.f) + hres.w;
    if (valid) *(float4*)&h[(size_t)vv * 64 + j0] = o;
    *(float4*)&hl[ln * 64 + j0] = o;          // deposit row for GEMM phase
    __syncthreads();
    // ---- next-layer GEMM from LDS: wave w -> nodes 4w..4w+3, 1 acc each ----
    int j = lane;
    for (int c = 0; c < 4; ++c) {
        int ln2 = wave * 4 + c;
        int v2 = blockIdx.x * 16 + ln2;
        if (v2 < n) {
            const float* hr = &hl[ln2 * 64];  // wave-uniform -> broadcast
            float acc = 0.f;
#pragma unroll
            for (int k = 0; k < 64; ++k) acc += hr[k] * wl[k * 64 + j];
            hws_out[(size_t)v2 * 64 + j] = f2bf(acc * dinv[v2]);
        }
    }
}

// gather + BN + ReLU + residual (layer 2), then MLP head.
__global__ void gather_mlp(const int* __restrict__ rowptr, const int* __restrict__ col,
                           const unsigned short* __restrict__ hws_in,
                           const float* __restrict__ dinv, const float* __restrict__ h,
                           const float* __restrict__ cb, const float* __restrict__ gamma,
                           const float* __restrict__ beta, const float* __restrict__ mean,
                           const float* __restrict__ var, const float* __restrict__ x,
                           const float* __restrict__ W1, const float* __restrict__ b1,
                           const float* __restrict__ W2, const float* __restrict__ b2,
                           float* __restrict__ out, int n) {
    __shared__ float wl[64 * 64];
    __shared__ float w2l[256];
    __shared__ float hl[16 * 64];
    __shared__ float tl[16 * 68];
    int tid = threadIdx.x;
#pragma unroll
    for (int i = 0; i < 16; ++i) wl[tid + 256 * i] = W1[tid + 256 * i];
    w2l[tid] = W2[tid];
    int lane = tid & 63, wave = tid >> 6;
    int grp = lane >> 4, gl = lane & 15;
    int ln = wave * 4 + grp;
    int v = blockIdx.x * 16 + ln;
    bool valid = v < n;
    int vv = valid ? v : 0;
    int j0 = gl * 4;
    const ushort4* hws4 = (const ushort4*)hws_in;
    ushort4 m = hws4[(size_t)vv * 16 + gl];
    float s0 = bf2f(m.x), s1 = bf2f(m.y), s2 = bf2f(m.z), s3 = bf2f(m.w);
    int beg = rowptr[vv];
    int end = valid ? rowptr[vv + 1] : beg;
    GATHER_BODY(hws4, col, beg, end, s0, s1, s2, s3, gl)
    float di = dinv[vv];
    float4 cbv = *(const float4*)&cb[j0];
    float4 mnv = *(const float4*)&mean[j0];
    float4 vrv = *(const float4*)&var[j0];
    float4 gmv = *(const float4*)&gamma[j0];
    float4 btv = *(const float4*)&beta[j0];
    float4 hres = *(const float4*)&h[(size_t)vv * 64 + j0];
    float4 o;
    o.x = fmaxf((s0 * di + cbv.x - mnv.x) * rsqrtf(vrv.x + 1e-5f) * gmv.x + btv.x, 0.f) + hres.x;
    o.y = fmaxf((s1 * di + cbv.y - mnv.y) * rsqrtf(vrv.y + 1e-5f) * gmv.y + btv.y, 0.f) + hres.y;
    o.z = fmaxf((s2 * di + cbv.z - mnv.z) * rsqrtf(vrv.z + 1e-5f) * gmv.z + btv.z, 0.f) + hres.z;
    o.w = fmaxf((s3 * di + cbv.w - mnv.w) * rsqrtf(vrv.w + 1e-5f) * gmv.w + btv.w, 0.f) + hres.w;
    *(float4*)&hl[ln * 64 + j0] = o;
    __syncthreads();
    // ---- t = relu(h@W1+b1): wave w -> nodes 4w..4w+3 ----
    int j = lane;
    float b1j = b1[j];
    for (int c = 0; c < 4; ++c) {
        int ln2 = wave * 4 + c;
        const float* hr = &hl[ln2 * 64];      // broadcast
        float acc = b1j;
#pragma unroll
        for (int k = 0; k < 64; ++k) acc += hr[k] * wl[k * 64 + j];
        tl[ln2 * 68 + j] = fmaxf(acc, 0.f);
    }
    __syncthreads();
    // ---- out = x + t@W2 + b2: 64 threads, one (node,m) each ----
    if (tid < 64) {
        int ln2 = tid >> 2, mm = tid & 3;
        int v2 = blockIdx.x * 16 + ln2;
        if (v2 < n) {
            const float* tr = &tl[ln2 * 68];
            float acc = b2[mm];
#pragma unroll
            for (int k = 0; k < 64; ++k) acc += tr[k] * w2l[k * 4 + mm];
            out[(size_t)v2 * 4 + mm] = x[(size_t)v2 * 4 + mm] + acc;
        }
    }
}

extern "C" void kernel_launch(void* const* d_in, const int* in_sizes, int n_in,
                              void* d_out, int out_size, void* d_ws, size_t ws_size,
                              hipStream_t stream) {
    const float* x     = (const float*)d_in[0];
    const int*   eidx  = (const int*)  d_in[1];
    const float* Win   = (const float*)d_in[2];
    const float* bin   = (const float*)d_in[3];
    const float* convw = (const float*)d_in[4];
    const float* convb = (const float*)d_in[5];
    const float* gamma = (const float*)d_in[6];
    const float* beta  = (const float*)d_in[7];
    const float* mean  = (const float*)d_in[8];
    const float* var   = (const float*)d_in[9];
    const float* W1    = (const float*)d_in[10];
    const float* b1    = (const float*)d_in[11];
    const float* W2    = (const float*)d_in[12];
    const float* b2    = (const float*)d_in[13];
    float* out = (float*)d_out;

    int n = in_sizes[0] / 4;   // 50000
    int E = in_sizes[1] / 2;   // 800000
    const int B = 256;
    int NB = (n + B - 1) / B;  // 196

    // workspace layout:
    // dinv[n] | h[n*64] | hws0[n*64] bf16 | hws1[n*64] bf16 | counts[n] |
    // cursor[n] | tmp[n] | rowptr[n+1] | bsum[256] | col[E]
    char* p = (char*)d_ws;
    size_t nh = (size_t)n * 64;
    float*          dinv   = (float*)p;          p += ((size_t)n + 16) * 4;
    float*          h      = (float*)p;          p += nh * 4;
    unsigned short* hws0   = (unsigned short*)p; p += nh * 2;
    unsigned short* hws1   = (unsigned short*)p; p += nh * 2;
    int*            counts = (int*)p;            p += (size_t)n * 4;
    int*            cursor = (int*)p;            p += (size_t)n * 4;
    int*            tmp    = (int*)p;            p += (size_t)n * 4;
    int*            rowptr = (int*)p;            p += ((size_t)n + 16) * 4;
    int*            bsum   = (int*)p;            p += 256 * 4;
    int*            col    = (int*)p;            p += (size_t)E * 4;

    const int GP = 128;                       // blocks per partition
    int fillBlocks = GP * 8;                  // 1024
    int nodes_per = (n + 7) / 8;
    int chunk = (E + GP - 1) / GP;

    // ---- CSR build head (4 dispatches incl. memset) ----
    hipMemsetAsync(counts, 0, (size_t)n * 4, stream);
    hist_part<<<fillBlocks, B, 0, stream>>>(eidx + E, counts, E, nodes_per, chunk);
    scan1<<<NB, B, 0, stream>>>(counts, tmp, bsum, dinv, n);
    scan3b<<<NB, B, 0, stream>>>(counts, tmp, bsum, rowptr, cursor, n, NB);

    // ---- fill + input GEMM fused (independent work, 1 dispatch) ----
    int NB32 = (n + 31) / 32;
    fill_gemm<<<fillBlocks + NB32, B, 0, stream>>>(
        eidx, cursor, col, E, n, nodes_per, chunk, fillBlocks,
        x, Win, bin, convw, dinv, h, hws0);

    // ---- layers (3 dispatches) ----
    int NB16 = (n + 15) / 16;
    gather_gemm<<<NB16, B, 0, stream>>>(rowptr, col, hws0, dinv, h,
        convb, gamma, beta, mean, var, convw + 4096, hws1, n);
    gather_gemm<<<NB16, B, 0, stream>>>(rowptr, col, hws1, dinv, h,
        convb + 64, gamma + 64, beta + 64, mean + 64, var + 64, convw + 8192, hws0, n);
    gather_mlp<<<NB16, B, 0, stream>>>(rowptr, col, hws0, dinv, h,
        convb + 128, gamma + 128, beta + 128, mean + 128, var + 128,
        x, W1, b1, W2, b2, out, n);
}